// Round 4
// baseline (337.941 us; speedup 1.0000x reference)
//
#include <hip/hip_runtime.h>
#include <hip/hip_bf16.h>

typedef unsigned short u16;
typedef unsigned int u32;
typedef __attribute__((ext_vector_type(8))) short bf16x8;
typedef __attribute__((ext_vector_type(4))) float f32x4;

#define T_STEPS 64
#define BN_TOT  8192
#define BM      32

// workspace byte offsets
#define OFF_WHH0  0u
#define OFF_WIH0  131072u
#define OFF_W1    163840u
#define OFF_B0    425984u
#define OFF_B1    428032u
#define OFF_WEFF  430080u
#define OFF_BEFF  432128u
#define OFF_XB    432192u

// LDS: whh0 kf0..2 frags (96KB) + 4 swizzled h buffers (8KB each)
#define LDS_W     98304
#define HB        8192
#define LDS_BYTES (LDS_W + 4*HB)   // 131072

__device__ __forceinline__ u16 f2bu(float f) {
  unsigned u = __float_as_uint(f);
  unsigned r = (u + 0x7FFFu + ((u >> 16) & 1u)) >> 16;
  return (u16)r;
}
__device__ __forceinline__ float bu2f(u16 u) {
  return __uint_as_float(((unsigned)u) << 16);
}
__device__ __forceinline__ float fsig(float x) {
  return __builtin_amdgcn_rcpf(1.0f + __builtin_amdgcn_exp2f(-1.44269504f * x));
}
__device__ __forceinline__ float ftanh(float x) {
  return 1.0f - 2.0f * __builtin_amdgcn_rcpf(__builtin_amdgcn_exp2f(2.88539008f * x) + 1.0f);
}
__device__ __forceinline__ unsigned cvt_pk_bf16(float lo, float hi) {
  unsigned r;
  asm("v_cvt_pk_bf16_f32 %0, %1, %2" : "=v"(r) : "v"(lo), "v"(hi));
  return r;
}
__device__ __forceinline__ f32x4 mfma16(bf16x8 a, bf16x8 b, f32x4 c) {
  return __builtin_amdgcn_mfma_f32_16x16x32_bf16(a, b, c, 0, 0, 0);
}
// XOR-swizzled byte offset into a 32x128 bf16 h-buffer (rows of 256B).
// Read (b128 per lane, rows vary per lane) and write use the same involution.
__device__ __forceinline__ int swz(int row, int bc) {
  return (row * 256 + bc) ^ ((row & 7) << 4);
}

union U16x8 { u16 u[8]; uint4 q; };

// ---------------- prep: weights -> fragment-ordered bf16, collapsed head ----
__global__ void lstm_prep_w(const float* Wih0, const float* Whh0,
                            const float* bih0, const float* bhh0,
                            const float* Wih1, const float* Whh1,
                            const float* bih1, const float* bhh1,
                            const float* muW1, const float* mub1,
                            const float* muW2, const float* mub2,
                            const float* sgW1, const float* sgb1,
                            const float* sgW2, const float* sgb2,
                            unsigned char* ws)
{
  int id = blockIdx.x * 256 + threadIdx.x;
  u16* whh0_f = (u16*)(ws + OFF_WHH0);
  u16* wih0_f = (u16*)(ws + OFF_WIH0);
  u16* w1_f   = (u16*)(ws + OFF_W1);
  float* b0   = (float*)(ws + OFF_B0);
  float* b1   = (float*)(ws + OFF_B1);
  float* weff = (float*)(ws + OFF_WEFF);
  float* beff = (float*)(ws + OFF_BEFF);

  if (id < 8192) {                       // Whh0 frags: [w][g][kf][lane][8]
    int fid = id >> 6, lane = id & 63;
    int w = fid >> 4, g = (fid >> 2) & 3, kf = fid & 3;
    int r = g*128 + w*16 + (lane & 15);
    int k = kf*32 + (lane >> 4)*8;
    const float* src = Whh0 + r*128 + k;
    U16x8 t;
    #pragma unroll
    for (int i = 0; i < 8; ++i) t.u[i] = f2bu(src[i]);
    ((uint4*)whh0_f)[id] = t.q;
  } else if (id < 10240) {               // Wih0 frags (K=8 in 32, zero-padded)
    int c = id - 8192; int fid = c >> 6, lane = c & 63;
    int w = fid >> 2, g = fid & 3;
    U16x8 t;
    #pragma unroll
    for (int i = 0; i < 8; ++i) t.u[i] = 0;
    if (lane < 16) {
      int r = g*128 + w*16 + lane;
      #pragma unroll
      for (int i = 0; i < 8; ++i) t.u[i] = f2bu(Wih0[r*8 + i]);
    }
    ((uint4*)wih0_f)[c] = t.q;
  } else if (id < 26624) {               // W1 = [Wih1 ; Whh1] frags, K=256
    int c = id - 10240; int fid = c >> 6, lane = c & 63;
    int w = fid >> 5, g = (fid >> 3) & 3, kf = fid & 7;
    int r = g*128 + w*16 + (lane & 15);
    int k = kf*32 + (lane >> 4)*8;
    const float* src = (k < 128) ? (Wih1 + r*128 + k) : (Whh1 + r*128 + (k-128));
    U16x8 t;
    #pragma unroll
    for (int i = 0; i < 8; ++i) t.u[i] = f2bu(src[i]);
    ((uint4*)w1_f)[c] = t.q;
  } else if (id < 27136) {               // b0 arranged
    int i = id - 26624; int w = i >> 6, g = (i >> 4) & 3, cc = i & 15;
    int r = g*128 + w*16 + cc;
    b0[i] = bih0[r] + bhh0[r];
  } else if (id < 27648) {               // b1 arranged
    int i = id - 27136; int w = i >> 6, g = (i >> 4) & 3, cc = i & 15;
    int r = g*128 + w*16 + cc;
    b1[i] = bih1[r] + bhh1[r];
  } else if (id < 28160) {               // collapsed head W: [4][128]
    int i = id - 27648; int o = i >> 7, k = i & 127;
    const float* W1p = (o < 2) ? muW1 : sgW1;
    const float* W2p = (o < 2) ? muW2 : sgW2;
    int oo = o & 1;
    float s = 0.f;
    for (int m = 0; m < 64; ++m) s += W2p[oo*64 + m] * W1p[m*128 + k];
    weff[i] = s;
  } else if (id < 28164) {               // collapsed head bias [4]
    int o = id - 28160; int oo = o & 1;
    const float* W2p = (o < 2) ? muW2 : sgW2;
    const float* b1p = (o < 2) ? mub1 : sgb1;
    const float* b2p = (o < 2) ? mub2 : sgb2;
    float s = b2p[oo];
    for (int m = 0; m < 64; ++m) s += W2p[oo*64 + m] * b1p[m];
    beff[o] = s;
  }
}

// ---------------- prep: in_tensor [B,T,N,D] fp32 -> xb [T, BN, 8] bf16 ------
__global__ void lstm_prep_x(const float* in, unsigned char* ws)
{
  int id = blockIdx.x * 256 + threadIdx.x;     // < 524288
  if (id >= T_STEPS * BN_TOT) return;
  int t = id >> 13, s = id & 8191, b = s >> 9, n = s & 511;
  const float* src = in + (((b*64) + t)*512 + n)*8;
  U16x8 v;
  #pragma unroll
  for (int i = 0; i < 8; ++i) v.u[i] = f2bu(src[i]);
  *(uint4*)(ws + OFF_XB + (size_t)id * 16) = v.q;
}

// ---------------- main: fused 2-layer LSTM + head, persistent over T --------
// ONE barrier per step. Window t: [L1m(t); act1(t); L0m(t+1); act0(t+1); bar].
// hA double-buffered: L1m(t) and L0m(t+1) read hA[t&1] (written by act0(t),
// previous window); act0(t+1) writes hA[(t+1)&1] (last read by L1m(t-1)/L0m(t),
// separated by bar(t-1->t)). hB: L1m(t) reads hB[(t-1)&1], act1(t) writes
// hB[t&1]. All cross-wave RAW/WAR pairs are separated by >=1 barrier.
#define ACT_BLOCK(ACC, CS, HBASE)                                   \
  { _Pragma("unroll")                                               \
    for (int mf = 0; mf < 2; ++mf) {                                \
      float hq[4];                                                  \
      _Pragma("unroll")                                             \
      for (int q = 0; q < 4; ++q) {                                 \
        float gi = fsig(ACC[mf][0][q]);                             \
        float gf = fsig(ACC[mf][1][q]);                             \
        float gg = ftanh(ACC[mf][2][q]);                            \
        float go = fsig(ACC[mf][3][q]);                             \
        float c  = gf * CS[mf][q] + gi * gg;                        \
        CS[mf][q] = c;                                              \
        hq[q] = go * ftanh(c);                                      \
      }                                                             \
      unsigned p01 = cvt_pk_bf16(hq[0], hq[1]);                     \
      unsigned p23 = cvt_pk_bf16(hq[2], hq[3]);                     \
      int r0 = mf*16 + lk*4;                                        \
      *(u16*)(HBASE + swz(r0,   wc2)) = (u16)p01;                   \
      *(u16*)(HBASE + swz(r0+1, wc2)) = (u16)(p01 >> 16);           \
      *(u16*)(HBASE + swz(r0+2, wc2)) = (u16)p23;                   \
      *(u16*)(HBASE + swz(r0+3, wc2)) = (u16)(p23 >> 16);           \
    } }

__global__ __launch_bounds__(512, 2) void lstm_fused(const unsigned char* ws, float* out)
{
  extern __shared__ unsigned char lds[];
  u16* whh0_lds = (u16*)lds;                 // [w][g][kf<3][lane][8] frags, 96KB
  unsigned char* hA0 = lds + LDS_W;
  unsigned char* hA1 = hA0 + HB;
  unsigned char* hB0 = hA1 + HB;
  unsigned char* hB1 = hB0 + HB;

  const u16* whh0_f = (const u16*)(ws + OFF_WHH0);
  const u16* wih0_f = (const u16*)(ws + OFF_WIH0);
  const u16* w1_f   = (const u16*)(ws + OFF_W1);
  const float* b0a  = (const float*)(ws + OFF_B0);
  const float* b1a  = (const float*)(ws + OFF_B1);
  const float* weff = (const float*)(ws + OFF_WEFF);
  const float* beff = (const float*)(ws + OFF_BEFF);
  const u16* xb     = (const u16*)(ws + OFF_XB);

  const int tid = threadIdx.x;
  const int w = tid >> 6, l = tid & 63;
  const int lrow = l & 15, lk = l >> 4;
  const int s0 = blockIdx.x * BM;
  const int wc2 = (w*16 + lrow) * 2;         // byte col this thread writes

  // stage whh0 kf0..2 into LDS (compact [w][g][kf<3] order)
  for (int i = tid; i < 6144; i += 512) {
    int f = i >> 6, l2 = i & 63;
    int ww = f / 12, r = f - ww*12, g = r / 3, kf = r - g*3;
    ((uint4*)whh0_lds)[i] = ((const uint4*)whh0_f)[((ww*16 + g*4 + kf) << 6) + l2];
  }
  // zero all four h buffers (contiguous 32KB)
  for (int i = tid; i < 8192; i += 512) ((u32*)hA0)[i] = 0;

  // persistent register weights
  bf16x8 w1r[4][8];
  #pragma unroll
  for (int g = 0; g < 4; ++g)
    #pragma unroll
    for (int kf = 0; kf < 8; ++kf)
      w1r[g][kf] = *(const bf16x8*)(w1_f + ((((w*4+g)*8)+kf)*64 + l)*8);
  bf16x8 wih0r[4];
  #pragma unroll
  for (int g = 0; g < 4; ++g)
    wih0r[g] = *(const bf16x8*)(wih0_f + ((w*4+g)*64 + l)*8);
  bf16x8 whh0r3[4];                          // whh0 kf=3 frags live in regs
  #pragma unroll
  for (int g = 0; g < 4; ++g)
    whh0r3[g] = *(const bf16x8*)(whh0_f + ((w*16 + g*4 + 3)*64 + l)*8);
  float b0v[4], b1v[4];
  #pragma unroll
  for (int g = 0; g < 4; ++g) {
    b0v[g] = b0a[w*64 + g*16 + lrow];
    b1v[g] = b1a[w*64 + g*16 + lrow];
  }
  float c_a[2][4] = {{0,0,0,0},{0,0,0,0}};
  float c_b[2][4] = {{0,0,0,0},{0,0,0,0}};

  unsigned char *haR = hA1, *haW = hA0;      // hA1 = zeros ("t=-1" state)
  unsigned char *hbR = hB1, *hbW = hB0;

  bf16x8 xf0 = {0,0,0,0,0,0,0,0}, xf1 = {0,0,0,0,0,0,0,0};
  if (lk == 0) {
    xf0 = *(const bf16x8*)(xb + (size_t)(s0 + lrow)*8);
    xf1 = *(const bf16x8*)(xb + (size_t)(s0 + 16 + lrow)*8);
  }
  __syncthreads();

  // ---- prologue: L0m(0) + act0(0) -> hA0 ----------------------------------
  {
    f32x4 acc0[2][4];
    #pragma unroll
    for (int g = 0; g < 4; ++g) {
      acc0[0][g] = (f32x4){b0v[g], b0v[g], b0v[g], b0v[g]};
      acc0[1][g] = (f32x4){b0v[g], b0v[g], b0v[g], b0v[g]};
    }
    #pragma unroll
    for (int g = 0; g < 4; ++g) {
      acc0[0][g] = mfma16(xf0, wih0r[g], acc0[0][g]);
      acc0[1][g] = mfma16(xf1, wih0r[g], acc0[1][g]);
    }
    #pragma unroll
    for (int kf = 0; kf < 4; ++kf) {
      int bc = kf*64 + lk*16;
      bf16x8 a0 = *(const bf16x8*)(haR + swz(lrow, bc));
      bf16x8 a1 = *(const bf16x8*)(haR + swz(16 + lrow, bc));
      #pragma unroll
      for (int g = 0; g < 4; ++g) {
        bf16x8 bfr = (kf < 3) ? *(const bf16x8*)(whh0_lds + (((w*4+g)*3 + kf)*64 + l)*8)
                              : whh0r3[g];
        acc0[0][g] = mfma16(a0, bfr, acc0[0][g]);
        acc0[1][g] = mfma16(a1, bfr, acc0[1][g]);
      }
    }
    if (lk == 0) {                           // xf <- x(1)
      xf0 = *(const bf16x8*)(xb + (size_t)(8192 + s0 + lrow)*8);
      xf1 = *(const bf16x8*)(xb + (size_t)(8192 + s0 + 16 + lrow)*8);
    }
    ACT_BLOCK(acc0, c_a, haW);
  }
  __syncthreads();
  { unsigned char* tp = haR; haR = haW; haW = tp; }   // haR = hA0 (state t=0)

  // ---- main loop: one barrier per step -------------------------------------
  #pragma unroll 1
  for (int t = 0; t < T_STEPS; ++t) {
    // L1m(t): gates1 = b1 + hA[t]@Wih1^T + hB[t-1]@Whh1^T (K=256 in regs)
    f32x4 acc1[2][4];
    #pragma unroll
    for (int g = 0; g < 4; ++g) {
      acc1[0][g] = (f32x4){b1v[g], b1v[g], b1v[g], b1v[g]};
      acc1[1][g] = (f32x4){b1v[g], b1v[g], b1v[g], b1v[g]};
    }
    #pragma unroll
    for (int kf = 0; kf < 8; ++kf) {
      const unsigned char* hs = (kf < 4) ? haR : hbR;
      int bc = (kf & 3)*64 + lk*16;
      bf16x8 a0 = *(const bf16x8*)(hs + swz(lrow, bc));
      bf16x8 a1 = *(const bf16x8*)(hs + swz(16 + lrow, bc));
      #pragma unroll
      for (int g = 0; g < 4; ++g) {
        acc1[0][g] = mfma16(a0, w1r[g][kf], acc1[0][g]);
        acc1[1][g] = mfma16(a1, w1r[g][kf], acc1[1][g]);
      }
    }
    ACT_BLOCK(acc1, c_b, hbW);               // act1(t) -> hB[t&1]

    if (t + 1 < T_STEPS) {
      // L0m(t+1): gates0 = b0 + x(t+1)@Wih0^T + hA[t]@Whh0^T
      f32x4 acc0[2][4];
      #pragma unroll
      for (int g = 0; g < 4; ++g) {
        acc0[0][g] = (f32x4){b0v[g], b0v[g], b0v[g], b0v[g]};
        acc0[1][g] = (f32x4){b0v[g], b0v[g], b0v[g], b0v[g]};
      }
      #pragma unroll
      for (int g = 0; g < 4; ++g) {
        acc0[0][g] = mfma16(xf0, wih0r[g], acc0[0][g]);
        acc0[1][g] = mfma16(xf1, wih0r[g], acc0[1][g]);
      }
      #pragma unroll
      for (int kf = 0; kf < 4; ++kf) {
        int bc = kf*64 + lk*16;
        bf16x8 a0 = *(const bf16x8*)(haR + swz(lrow, bc));
        bf16x8 a1 = *(const bf16x8*)(haR + swz(16 + lrow, bc));
        #pragma unroll
        for (int g = 0; g < 4; ++g) {
          bf16x8 bfr = (kf < 3) ? *(const bf16x8*)(whh0_lds + (((w*4+g)*3 + kf)*64 + l)*8)
                                : whh0r3[g];
          acc0[0][g] = mfma16(a0, bfr, acc0[0][g]);
          acc0[1][g] = mfma16(a1, bfr, acc0[1][g]);
        }
      }
      if (t + 2 < T_STEPS && lk == 0) {      // prefetch x(t+2)
        xf0 = *(const bf16x8*)(xb + (size_t)((t+2)*8192 + s0 + lrow)*8);
        xf1 = *(const bf16x8*)(xb + (size_t)((t+2)*8192 + s0 + 16 + lrow)*8);
      }
      ACT_BLOCK(acc0, c_a, haW);             // act0(t+1) -> hA[(t+1)&1]
    }
    __syncthreads();                         // the ONE barrier per step
    { unsigned char* tp = haR; haR = haW; haW = tp; }
    { unsigned char* tp = hbR; hbR = hbW; hbW = tp; }
  }

  // ---- head: out = sigmoid(h_final @ Weff^T + beff), sigma *= 0.5 ----------
  if (tid < BM*4) {
    int m = tid >> 2, o = tid & 3;
    const float* wr = weff + o*128;
    float d = beff[o];
    #pragma unroll 4
    for (int kk = 0; kk < 16; ++kk) {
      bf16x8 hv = *(const bf16x8*)(hbR + swz(m, kk*16));
      #pragma unroll
      for (int j = 0; j < 8; ++j) d += bu2f((u16)hv[j]) * wr[kk*8 + j];
    }
    float v = fsig(d);
    if (o >= 2) v *= 0.5f;
    int s = s0 + m;
    out[(o >= 2 ? 16384 : 0) + s*2 + (o & 1)] = v;
  }
}

extern "C" void kernel_launch(void* const* d_in, const int* in_sizes, int n_in,
                              void* d_out, int out_size, void* d_ws, size_t ws_size,
                              hipStream_t stream) {
  (void)in_sizes; (void)n_in; (void)out_size; (void)ws_size;
  const float* in_tensor = (const float*)d_in[0];
  const float* Wih0 = (const float*)d_in[1];
  const float* Whh0 = (const float*)d_in[2];
  const float* bih0 = (const float*)d_in[3];
  const float* bhh0 = (const float*)d_in[4];
  const float* Wih1 = (const float*)d_in[5];
  const float* Whh1 = (const float*)d_in[6];
  const float* bih1 = (const float*)d_in[7];
  const float* bhh1 = (const float*)d_in[8];
  const float* muW1 = (const float*)d_in[9];
  const float* mub1 = (const float*)d_in[10];
  const float* muW2 = (const float*)d_in[11];
  const float* mub2 = (const float*)d_in[12];
  const float* sgW1 = (const float*)d_in[13];
  const float* sgb1 = (const float*)d_in[14];
  const float* sgW2 = (const float*)d_in[15];
  const float* sgb2 = (const float*)d_in[16];
  unsigned char* ws = (unsigned char*)d_ws;
  float* out = (float*)d_out;

  lstm_prep_w<<<dim3(111), dim3(256), 0, stream>>>(
      Wih0, Whh0, bih0, bhh0, Wih1, Whh1, bih1, bhh1,
      muW1, mub1, muW2, mub2, sgW1, sgb1, sgW2, sgb2, ws);
  lstm_prep_x<<<dim3(2048), dim3(256), 0, stream>>>(in_tensor, ws);

  (void)hipFuncSetAttribute((const void*)lstm_fused,
                            hipFuncAttributeMaxDynamicSharedMemorySize, LDS_BYTES);
  lstm_fused<<<dim3(256), dim3(512), LDS_BYTES, stream>>>(ws, out);
}

// Round 5
// 329.095 us; speedup vs baseline: 1.0269x; 1.0269x over previous
//
#include <hip/hip_runtime.h>
#include <hip/hip_bf16.h>

typedef unsigned short u16;
typedef unsigned int u32;
typedef __attribute__((ext_vector_type(8))) short bf16x8;
typedef __attribute__((ext_vector_type(4))) float f32x4;
typedef __attribute__((ext_vector_type(4))) unsigned u32x4;

#define T_STEPS 64
#define BN_TOT  8192
#define BM      32

// workspace byte offsets
#define OFF_WHH0  0u
#define OFF_WIH0  131072u
#define OFF_W1    163840u
#define OFF_B0    425984u
#define OFF_B1    428032u
#define OFF_WEFF  430080u
#define OFF_BEFF  432128u
#define OFF_XB    432192u

// LDS: whh0 frags (128KB) + 3 h buffers (8KB each, col-block-major)
#define HB        8192
#define LDS_BYTES (131072 + 3*HB)   // 155648

__device__ __forceinline__ u16 f2bu(float f) {
  unsigned u = __float_as_uint(f);
  unsigned r = (u + 0x7FFFu + ((u >> 16) & 1u)) >> 16;
  return (u16)r;
}
__device__ __forceinline__ float bu2f(u16 u) {
  return __uint_as_float(((unsigned)u) << 16);
}
__device__ __forceinline__ float fsig(float x) {
  return __builtin_amdgcn_rcpf(1.0f + __builtin_amdgcn_exp2f(-1.44269504f * x));
}
__device__ __forceinline__ float ftanh(float x) {
  return 1.0f - 2.0f * __builtin_amdgcn_rcpf(__builtin_amdgcn_exp2f(2.88539008f * x) + 1.0f);
}
__device__ __forceinline__ unsigned cvt_pk_bf16(float lo, float hi) {
  unsigned r;
  asm("v_cvt_pk_bf16_f32 %0, %1, %2" : "=v"(r) : "v"(lo), "v"(hi));
  return r;
}
__device__ __forceinline__ f32x4 mfma16(bf16x8 a, bf16x8 b, f32x4 c) {
  return __builtin_amdgcn_mfma_f32_16x16x32_bf16(a, b, c, 0, 0, 0);
}
// MFMA with B operand pinned in AGPRs ("a" constraint) -> W1 stays resident
// in the accumulator file, zero VGPR pressure, zero shuttle VALU.
__device__ __forceinline__ void mfma_agpr(f32x4& c, const bf16x8& a, const u32x4& b) {
  asm("v_mfma_f32_16x16x32_bf16 %0, %1, %2, %0" : "+v"(c) : "v"(a), "a"(b));
}

union U16x8 { u16 u[8]; uint4 q; };

// ---------------- prep: weights -> fragment-ordered bf16, collapsed head ----
__global__ void lstm_prep_w(const float* Wih0, const float* Whh0,
                            const float* bih0, const float* bhh0,
                            const float* Wih1, const float* Whh1,
                            const float* bih1, const float* bhh1,
                            const float* muW1, const float* mub1,
                            const float* muW2, const float* mub2,
                            const float* sgW1, const float* sgb1,
                            const float* sgW2, const float* sgb2,
                            unsigned char* ws)
{
  int id = blockIdx.x * 256 + threadIdx.x;
  u16* whh0_f = (u16*)(ws + OFF_WHH0);
  u16* wih0_f = (u16*)(ws + OFF_WIH0);
  u16* w1_f   = (u16*)(ws + OFF_W1);
  float* b0   = (float*)(ws + OFF_B0);
  float* b1   = (float*)(ws + OFF_B1);
  float* weff = (float*)(ws + OFF_WEFF);
  float* beff = (float*)(ws + OFF_BEFF);

  if (id < 8192) {                       // Whh0 frags: [w][g][kf][lane][8]
    int fid = id >> 6, lane = id & 63;
    int w = fid >> 4, g = (fid >> 2) & 3, kf = fid & 3;
    int r = g*128 + w*16 + (lane & 15);
    int k = kf*32 + (lane >> 4)*8;
    const float* src = Whh0 + r*128 + k;
    U16x8 t;
    #pragma unroll
    for (int i = 0; i < 8; ++i) t.u[i] = f2bu(src[i]);
    ((uint4*)whh0_f)[id] = t.q;
  } else if (id < 10240) {               // Wih0 frags (K=8 in 32, zero-padded)
    int c = id - 8192; int fid = c >> 6, lane = c & 63;
    int w = fid >> 2, g = fid & 3;
    U16x8 t;
    #pragma unroll
    for (int i = 0; i < 8; ++i) t.u[i] = 0;
    if (lane < 16) {
      int r = g*128 + w*16 + lane;
      #pragma unroll
      for (int i = 0; i < 8; ++i) t.u[i] = f2bu(Wih0[r*8 + i]);
    }
    ((uint4*)wih0_f)[c] = t.q;
  } else if (id < 26624) {               // W1 = [Wih1 ; Whh1] frags, K=256
    int c = id - 10240; int fid = c >> 6, lane = c & 63;
    int w = fid >> 5, g = (fid >> 3) & 3, kf = fid & 7;
    int r = g*128 + w*16 + (lane & 15);
    int k = kf*32 + (lane >> 4)*8;
    const float* src = (k < 128) ? (Wih1 + r*128 + k) : (Whh1 + r*128 + (k-128));
    U16x8 t;
    #pragma unroll
    for (int i = 0; i < 8; ++i) t.u[i] = f2bu(src[i]);
    ((uint4*)w1_f)[c] = t.q;
  } else if (id < 27136) {               // b0 arranged
    int i = id - 26624; int w = i >> 6, g = (i >> 4) & 3, cc = i & 15;
    int r = g*128 + w*16 + cc;
    b0[i] = bih0[r] + bhh0[r];
  } else if (id < 27648) {               // b1 arranged
    int i = id - 27136; int w = i >> 6, g = (i >> 4) & 3, cc = i & 15;
    int r = g*128 + w*16 + cc;
    b1[i] = bih1[r] + bhh1[r];
  } else if (id < 28160) {               // collapsed head W: [4][128]
    int i = id - 27648; int o = i >> 7, k = i & 127;
    const float* W1p = (o < 2) ? muW1 : sgW1;
    const float* W2p = (o < 2) ? muW2 : sgW2;
    int oo = o & 1;
    float s = 0.f;
    for (int m = 0; m < 64; ++m) s += W2p[oo*64 + m] * W1p[m*128 + k];
    weff[i] = s;
  } else if (id < 28164) {               // collapsed head bias [4]
    int o = id - 28160; int oo = o & 1;
    const float* W2p = (o < 2) ? muW2 : sgW2;
    const float* b1p = (o < 2) ? mub1 : sgb1;
    const float* b2p = (o < 2) ? mub2 : sgb2;
    float s = b2p[oo];
    for (int m = 0; m < 64; ++m) s += W2p[oo*64 + m] * b1p[m];
    beff[o] = s;
  }
}

// ---------------- prep: in_tensor [B,T,N,D] fp32 -> xb [T, BN, 8] bf16 ------
__global__ void lstm_prep_x(const float* in, unsigned char* ws)
{
  int id = blockIdx.x * 256 + threadIdx.x;     // < 524288
  if (id >= T_STEPS * BN_TOT) return;
  int t = id >> 13, s = id & 8191, b = s >> 9, n = s & 511;
  const float* src = in + (((b*64) + t)*512 + n)*8;
  U16x8 v;
  #pragma unroll
  for (int i = 0; i < 8; ++i) v.u[i] = f2bu(src[i]);
  *(uint4*)(ws + OFF_XB + (size_t)id * 16) = v.q;
}

// ---------------- main: fused 2-layer LSTM + head, persistent over T --------
// h buffers are COLUMN-BLOCK-MAJOR: addr(r, c) = (c>>3)*512 + r*16 + (c&7)*2.
// A-frag read (quarter lk): 16 lanes x contiguous 256B  -> conflict-free.
// ACT write: 64 u16 over 128B = 2 lanes/bank            -> conflict-free.
// (R1-R4 layouts were 8-way conflicted: SQ_LDS_BANK_CONFLICT const 1.26e7.)
#define ACT_BLOCK(ACC, CS, HBASE)                                   \
  { _Pragma("unroll")                                               \
    for (int mf = 0; mf < 2; ++mf) {                                \
      float hq[4];                                                  \
      _Pragma("unroll")                                             \
      for (int q = 0; q < 4; ++q) {                                 \
        float gi = fsig(ACC[mf][0][q]);                             \
        float gf = fsig(ACC[mf][1][q]);                             \
        float gg = ftanh(ACC[mf][2][q]);                            \
        float go = fsig(ACC[mf][3][q]);                             \
        float c  = gf * CS[mf][q] + gi * gg;                        \
        CS[mf][q] = c;                                              \
        hq[q] = go * ftanh(c);                                      \
      }                                                             \
      unsigned p01 = cvt_pk_bf16(hq[0], hq[1]);                     \
      unsigned p23 = cvt_pk_bf16(hq[2], hq[3]);                     \
      int r0 = mf*16 + lk*4;                                        \
      *(u16*)(HBASE + wb + (r0  )*16) = (u16)p01;                   \
      *(u16*)(HBASE + wb + (r0+1)*16) = (u16)(p01 >> 16);           \
      *(u16*)(HBASE + wb + (r0+2)*16) = (u16)p23;                   \
      *(u16*)(HBASE + wb + (r0+3)*16) = (u16)(p23 >> 16);           \
    } }

__global__ __launch_bounds__(512, 2) void lstm_fused(const unsigned char* ws, float* out)
{
  extern __shared__ unsigned char lds[];
  u16* whh0_lds = (u16*)lds;                 // [w][g][kf][lane][8] frags, 128KB
  unsigned char* hA  = lds + 131072;
  unsigned char* hB0 = hA + HB;
  unsigned char* hB1 = hB0 + HB;

  const u16* whh0_f = (const u16*)(ws + OFF_WHH0);
  const u16* wih0_f = (const u16*)(ws + OFF_WIH0);
  const u16* w1_f   = (const u16*)(ws + OFF_W1);
  const float* b0a  = (const float*)(ws + OFF_B0);
  const float* b1a  = (const float*)(ws + OFF_B1);
  const float* weff = (const float*)(ws + OFF_WEFF);
  const float* beff = (const float*)(ws + OFF_BEFF);
  const u16* xb     = (const u16*)(ws + OFF_XB);

  const int tid = threadIdx.x;
  const int w = tid >> 6, l = tid & 63;
  const int lrow = l & 15, lk = l >> 4;
  const int s0 = blockIdx.x * BM;
  // per-thread byte bases into col-block-major h buffers
  const int wb = (w*2 + (lrow >> 3))*512 + (lrow & 7)*2;   // ACT write base
  const int ra = lk*512 + lrow*16;                          // A-read base

  // stage Whh0 frags into LDS (straight 16B copies)
  for (int i = tid; i < 8192; i += 512)
    ((uint4*)whh0_lds)[i] = ((const uint4*)whh0_f)[i];
  // zero all three h buffers (contiguous 24KB)
  for (int i = tid; i < 6144; i += 512) ((u32*)hA)[i] = 0;

  // W1 frags pinned into AGPRs: only consumers are "a"-constrained asm MFMAs.
  u32x4 w1a[4][8];
  #pragma unroll
  for (int g = 0; g < 4; ++g)
    #pragma unroll
    for (int kf = 0; kf < 8; ++kf)
      w1a[g][kf] = *(const u32x4*)(w1_f + ((((w*4+g)*8)+kf)*64 + l)*8);
  bf16x8 wih0r[4];
  #pragma unroll
  for (int g = 0; g < 4; ++g)
    wih0r[g] = *(const bf16x8*)(wih0_f + ((w*4+g)*64 + l)*8);
  float b0v[4], b1v[4];
  #pragma unroll
  for (int g = 0; g < 4; ++g) {
    b0v[g] = b0a[w*64 + g*16 + lrow];
    b1v[g] = b1a[w*64 + g*16 + lrow];
  }
  float c_a[2][4] = {{0,0,0,0},{0,0,0,0}};
  float c_b[2][4] = {{0,0,0,0},{0,0,0,0}};

  unsigned char* hbR = hB0;   // layer-1 h_prev (zero at t=0)
  unsigned char* hbW = hB1;

  bf16x8 xf0 = {0,0,0,0,0,0,0,0}, xf1 = {0,0,0,0,0,0,0,0};
  if (lk == 0) {
    xf0 = *(const bf16x8*)(xb + (size_t)(s0 + lrow)*8);
    xf1 = *(const bf16x8*)(xb + (size_t)(s0 + 16 + lrow)*8);
  }
  __syncthreads();

  #pragma unroll 1
  for (int t = 0; t < T_STEPS; ++t) {
    // ---- layer 0: gates = b0 + x@Wih0^T + hA@Whh0^T ------------------------
    f32x4 acc[2][4];
    #pragma unroll
    for (int g = 0; g < 4; ++g) {
      acc[0][g] = (f32x4){b0v[g], b0v[g], b0v[g], b0v[g]};
      acc[1][g] = (f32x4){b0v[g], b0v[g], b0v[g], b0v[g]};
    }
    #pragma unroll
    for (int g = 0; g < 4; ++g) {
      acc[0][g] = mfma16(xf0, wih0r[g], acc[0][g]);
      acc[1][g] = mfma16(xf1, wih0r[g], acc[1][g]);
    }
    // prefetch next step's x
    if (t + 1 < T_STEPS && lk == 0) {
      xf0 = *(const bf16x8*)(xb + (size_t)((t+1)*8192 + s0 + lrow)*8);
      xf1 = *(const bf16x8*)(xb + (size_t)((t+1)*8192 + s0 + 16 + lrow)*8);
    }
    #pragma unroll
    for (int kf = 0; kf < 4; ++kf) {
      bf16x8 a0 = *(const bf16x8*)(hA + (kf*4)*512 + ra);
      bf16x8 a1 = *(const bf16x8*)(hA + (kf*4)*512 + ra + 256);
      #pragma unroll
      for (int g = 0; g < 4; ++g) {
        bf16x8 bfr = *(const bf16x8*)(whh0_lds + ((w*16 + g*4 + kf)*64 + l)*8);
        acc[0][g] = mfma16(a0, bfr, acc[0][g]);
        acc[1][g] = mfma16(a1, bfr, acc[1][g]);
      }
    }
    __syncthreads();                       // (1) WAR: hA reads done
    ACT_BLOCK(acc, c_a, hA);               // act0 -> hA (new h, layer 0)
    __syncthreads();                       // (2) RAW: new hA visible

    // ---- layer 1: gates = b1 + hA@Wih1^T + hbR@Whh1^T (W1 in AGPRs) -------
    #pragma unroll
    for (int g = 0; g < 4; ++g) {
      acc[0][g] = (f32x4){b1v[g], b1v[g], b1v[g], b1v[g]};
      acc[1][g] = (f32x4){b1v[g], b1v[g], b1v[g], b1v[g]};
    }
    asm volatile("s_nop 1");               // VALU-splat -> asm MFMA C-read gap
    #pragma unroll
    for (int kf = 0; kf < 8; ++kf) {
      const unsigned char* hs = (kf < 4) ? hA : hbR;
      int cb = (kf & 3)*4;
      bf16x8 a0 = *(const bf16x8*)(hs + cb*512 + ra);
      bf16x8 a1 = *(const bf16x8*)(hs + cb*512 + ra + 256);
      #pragma unroll
      for (int g = 0; g < 4; ++g) {
        mfma_agpr(acc[0][g], a0, w1a[g][kf]);
        mfma_agpr(acc[1][g], a1, w1a[g][kf]);
      }
    }
    asm volatile("s_nop 7\ns_nop 7");      // asm MFMA -> VALU read of acc
    // writes go to hbW (ping-pong): next step's bars order them vs t+1 readers
    ACT_BLOCK(acc, c_b, hbW);              // act1 -> hB[t&1]
    { unsigned char* tp = hbR; hbR = hbW; hbW = tp; }
  }
  __syncthreads();                         // final hB visible for the head

  // ---- head: out = sigmoid(h_final @ Weff^T + beff), sigma *= 0.5 ----------
  if (tid < BM*4) {
    int m = tid >> 2, o = tid & 3;
    const float* wr = weff + o*128;
    float d = beff[o];
    #pragma unroll 4
    for (int kk = 0; kk < 16; ++kk) {
      bf16x8 hv = *(const bf16x8*)(hbR + kk*512 + m*16);
      #pragma unroll
      for (int j = 0; j < 8; ++j) d += bu2f((u16)hv[j]) * wr[kk*8 + j];
    }
    float v = fsig(d);
    if (o >= 2) v *= 0.5f;
    int s = s0 + m;
    out[(o >= 2 ? 16384 : 0) + s*2 + (o & 1)] = v;
  }
}

extern "C" void kernel_launch(void* const* d_in, const int* in_sizes, int n_in,
                              void* d_out, int out_size, void* d_ws, size_t ws_size,
                              hipStream_t stream) {
  (void)in_sizes; (void)n_in; (void)out_size; (void)ws_size;
  const float* in_tensor = (const float*)d_in[0];
  const float* Wih0 = (const float*)d_in[1];
  const float* Whh0 = (const float*)d_in[2];
  const float* bih0 = (const float*)d_in[3];
  const float* bhh0 = (const float*)d_in[4];
  const float* Wih1 = (const float*)d_in[5];
  const float* Whh1 = (const float*)d_in[6];
  const float* bih1 = (const float*)d_in[7];
  const float* bhh1 = (const float*)d_in[8];
  const float* muW1 = (const float*)d_in[9];
  const float* mub1 = (const float*)d_in[10];
  const float* muW2 = (const float*)d_in[11];
  const float* mub2 = (const float*)d_in[12];
  const float* sgW1 = (const float*)d_in[13];
  const float* sgb1 = (const float*)d_in[14];
  const float* sgW2 = (const float*)d_in[15];
  const float* sgb2 = (const float*)d_in[16];
  unsigned char* ws = (unsigned char*)d_ws;
  float* out = (float*)d_out;

  lstm_prep_w<<<dim3(111), dim3(256), 0, stream>>>(
      Wih0, Whh0, bih0, bhh0, Wih1, Whh1, bih1, bhh1,
      muW1, mub1, muW2, mub2, sgW1, sgb1, sgW2, sgb2, ws);
  lstm_prep_x<<<dim3(2048), dim3(256), 0, stream>>>(in_tensor, ws);

  (void)hipFuncSetAttribute((const void*)lstm_fused,
                            hipFuncAttributeMaxDynamicSharedMemorySize, LDS_BYTES);
  lstm_fused<<<dim3(256), dim3(512), LDS_BYTES, stream>>>(ws, out);
}

// Round 6
// 328.879 us; speedup vs baseline: 1.0276x; 1.0007x over previous
//
#include <hip/hip_runtime.h>
#include <hip/hip_bf16.h>

typedef unsigned short u16;
typedef unsigned int u32;
typedef __attribute__((ext_vector_type(8))) short bf16x8;
typedef __attribute__((ext_vector_type(4))) float f32x4;
typedef __attribute__((ext_vector_type(4))) unsigned u32x4;

#define T_STEPS 64
#define BN_TOT  8192
#define BM      32

// workspace byte offsets
#define OFF_WHH0  0u
#define OFF_WIH0  131072u
#define OFF_W1    163840u
#define OFF_B0    425984u
#define OFF_B1    428032u
#define OFF_WEFF  430080u
#define OFF_BEFF  432128u
#define OFF_XB    432192u

// LDS: whh0 frags (128KB) + 3 h buffers (8KB each, col-block-major permuted)
#define HB        8192
#define LDS_BYTES (131072 + 3*HB)   // 155648

__device__ __forceinline__ u16 f2bu(float f) {
  unsigned u = __float_as_uint(f);
  unsigned r = (u + 0x7FFFu + ((u >> 16) & 1u)) >> 16;
  return (u16)r;
}
__device__ __forceinline__ float bu2f(u16 u) {
  return __uint_as_float(((unsigned)u) << 16);
}
__device__ __forceinline__ float fsig(float x) {
  return __builtin_amdgcn_rcpf(1.0f + __builtin_amdgcn_exp2f(-1.44269504f * x));
}
__device__ __forceinline__ float ftanh(float x) {
  return 1.0f - 2.0f * __builtin_amdgcn_rcpf(__builtin_amdgcn_exp2f(2.88539008f * x) + 1.0f);
}
__device__ __forceinline__ unsigned cvt_pk_bf16(float lo, float hi) {
  unsigned r;
  asm("v_cvt_pk_bf16_f32 %0, %1, %2" : "=v"(r) : "v"(lo), "v"(hi));
  return r;
}
__device__ __forceinline__ f32x4 mfma16(bf16x8 a, bf16x8 b, f32x4 c) {
  return __builtin_amdgcn_mfma_f32_16x16x32_bf16(a, b, c, 0, 0, 0);
}
// MFMA with B operand pinned in AGPRs -> W1 resident in accumulator file.
__device__ __forceinline__ void mfma_agpr(f32x4& c, const bf16x8& a, const u32x4& b) {
  asm("v_mfma_f32_16x16x32_bf16 %0, %1, %2, %0" : "+v"(c) : "v"(a), "a"(b));
}

union U16x8 { u16 u[8]; uint4 q; };

// ---------------- prep: weights -> fragment-ordered bf16, collapsed head ----
__global__ void lstm_prep_w(const float* Wih0, const float* Whh0,
                            const float* bih0, const float* bhh0,
                            const float* Wih1, const float* Whh1,
                            const float* bih1, const float* bhh1,
                            const float* muW1, const float* mub1,
                            const float* muW2, const float* mub2,
                            const float* sgW1, const float* sgb1,
                            const float* sgW2, const float* sgb2,
                            unsigned char* ws)
{
  int id = blockIdx.x * 256 + threadIdx.x;
  u16* whh0_f = (u16*)(ws + OFF_WHH0);
  u16* wih0_f = (u16*)(ws + OFF_WIH0);
  u16* w1_f   = (u16*)(ws + OFF_W1);
  float* b0   = (float*)(ws + OFF_B0);
  float* b1   = (float*)(ws + OFF_B1);
  float* weff = (float*)(ws + OFF_WEFF);
  float* beff = (float*)(ws + OFF_BEFF);

  if (id < 8192) {                       // Whh0 frags: [w][g][kf][lane][8]
    int fid = id >> 6, lane = id & 63;
    int w = fid >> 4, g = (fid >> 2) & 3, kf = fid & 3;
    int r = g*128 + w*16 + (lane & 15);
    int k = kf*32 + (lane >> 4)*8;
    const float* src = Whh0 + r*128 + k;
    U16x8 t;
    #pragma unroll
    for (int i = 0; i < 8; ++i) t.u[i] = f2bu(src[i]);
    ((uint4*)whh0_f)[id] = t.q;
  } else if (id < 10240) {               // Wih0 frags (K=8 in 32, zero-padded)
    int c = id - 8192; int fid = c >> 6, lane = c & 63;
    int w = fid >> 2, g = fid & 3;
    U16x8 t;
    #pragma unroll
    for (int i = 0; i < 8; ++i) t.u[i] = 0;
    if (lane < 16) {
      int r = g*128 + w*16 + lane;
      #pragma unroll
      for (int i = 0; i < 8; ++i) t.u[i] = f2bu(Wih0[r*8 + i]);
    }
    ((uint4*)wih0_f)[c] = t.q;
  } else if (id < 26624) {               // W1 = [Wih1 ; Whh1] frags, K=256
    int c = id - 10240; int fid = c >> 6, lane = c & 63;
    int w = fid >> 5, g = (fid >> 3) & 3, kf = fid & 7;
    int r = g*128 + w*16 + (lane & 15);
    int k = kf*32 + (lane >> 4)*8;
    const float* src = (k < 128) ? (Wih1 + r*128 + k) : (Whh1 + r*128 + (k-128));
    U16x8 t;
    #pragma unroll
    for (int i = 0; i < 8; ++i) t.u[i] = f2bu(src[i]);
    ((uint4*)w1_f)[c] = t.q;
  } else if (id < 27136) {               // b0 arranged
    int i = id - 26624; int w = i >> 6, g = (i >> 4) & 3, cc = i & 15;
    int r = g*128 + w*16 + cc;
    b0[i] = bih0[r] + bhh0[r];
  } else if (id < 27648) {               // b1 arranged
    int i = id - 27136; int w = i >> 6, g = (i >> 4) & 3, cc = i & 15;
    int r = g*128 + w*16 + cc;
    b1[i] = bih1[r] + bhh1[r];
  } else if (id < 28160) {               // collapsed head W: [4][128]
    int i = id - 27648; int o = i >> 7, k = i & 127;
    const float* W1p = (o < 2) ? muW1 : sgW1;
    const float* W2p = (o < 2) ? muW2 : sgW2;
    int oo = o & 1;
    float s = 0.f;
    for (int m = 0; m < 64; ++m) s += W2p[oo*64 + m] * W1p[m*128 + k];
    weff[i] = s;
  } else if (id < 28164) {               // collapsed head bias [4]
    int o = id - 28160; int oo = o & 1;
    const float* W2p = (o < 2) ? muW2 : sgW2;
    const float* b1p = (o < 2) ? mub1 : sgb1;
    const float* b2p = (o < 2) ? mub2 : sgb2;
    float s = b2p[oo];
    for (int m = 0; m < 64; ++m) s += W2p[oo*64 + m] * b1p[m];
    beff[o] = s;
  }
}

// ---------------- prep: in_tensor [B,T,N,D] fp32 -> xb [T, BN, 8] bf16 ------
__global__ void lstm_prep_x(const float* in, unsigned char* ws)
{
  int id = blockIdx.x * 256 + threadIdx.x;     // < 524288
  if (id >= T_STEPS * BN_TOT) return;
  int t = id >> 13, s = id & 8191, b = s >> 9, n = s & 511;
  const float* src = in + (((b*64) + t)*512 + n)*8;
  U16x8 v;
  #pragma unroll
  for (int i = 0; i < 8; ++i) v.u[i] = f2bu(src[i]);
  *(uint4*)(ws + OFF_XB + (size_t)id * 16) = v.q;
}

// ---------------- main: fused 2-layer LSTM + head, persistent over T --------
// h layout: col-block-major with permuted+XOR'd rows.
//   seq = mf*16 + lk*4 + q  is stored at physical row  mf*16 + ((q*4+lk) ^ (cb&7))
//   addr(seq, col) = cb*512 + row_phys*16 + (col&7)*2,  cb = col>>3.
// ACT u16 stores: lanes spread (row&7 x lo/2) over all 32 banks -> 2-way, free.
// A-frag b128 reads: 16 lanes hit 16 distinct rows -> 2-way, free.
#define ACT_BLOCK(ACC, CS, HBASE)                                      \
  { _Pragma("unroll")                                                  \
    for (int mf = 0; mf < 2; ++mf) {                                   \
      float hq[4];                                                     \
      _Pragma("unroll")                                                \
      for (int q = 0; q < 4; ++q) {                                    \
        float gi = fsig(ACC[mf][0][q]);                                \
        float gf = fsig(ACC[mf][1][q]);                                \
        float gg = ftanh(ACC[mf][2][q]);                               \
        float go = fsig(ACC[mf][3][q]);                                \
        float c  = gf * CS[mf][q] + gi * gg;                           \
        CS[mf][q] = c;                                                 \
        hq[q] = go * ftanh(c);                                         \
      }                                                                \
      unsigned p01 = cvt_pk_bf16(hq[0], hq[1]);                        \
      unsigned p23 = cvt_pk_bf16(hq[2], hq[3]);                        \
      int rb = mf*16;                                                  \
      *(u16*)(HBASE + wbase + (rb + ((lk     ) ^ wkey))*16) = (u16)p01;        \
      *(u16*)(HBASE + wbase + (rb + ((lk + 4 ) ^ wkey))*16) = (u16)(p01 >> 16);\
      *(u16*)(HBASE + wbase + (rb + ((lk + 8 ) ^ wkey))*16) = (u16)p23;        \
      *(u16*)(HBASE + wbase + (rb + ((lk + 12) ^ wkey))*16) = (u16)(p23 >> 16);\
    } }

__global__ __launch_bounds__(512, 2) void lstm_fused(const unsigned char* ws, float* out)
{
  extern __shared__ unsigned char lds[];
  u16* whh0_lds = (u16*)lds;                 // [w][g][kf][lane][8] frags, 128KB
  unsigned char* hA  = lds + 131072;
  unsigned char* hB0 = hA + HB;
  unsigned char* hB1 = hB0 + HB;

  const u16* whh0_f = (const u16*)(ws + OFF_WHH0);
  const u16* wih0_f = (const u16*)(ws + OFF_WIH0);
  const u16* w1_f   = (const u16*)(ws + OFF_W1);
  const float* b0a  = (const float*)(ws + OFF_B0);
  const float* b1a  = (const float*)(ws + OFF_B1);
  const float* weff = (const float*)(ws + OFF_WEFF);
  const float* beff = (const float*)(ws + OFF_BEFF);
  const u16* xb     = (const u16*)(ws + OFF_XB);

  const int tid = threadIdx.x;
  const int w = tid >> 6, l = tid & 63;
  const int lrow = l & 15, lk = l >> 4;
  const int s0 = blockIdx.x * BM;

  // write-side addressing (this thread's h column = w*16 + lrow)
  const int cbw   = w*2 + (lrow >> 3);          // col-block
  const int wkey  = cbw & 7;                    // XOR key
  const int wbase = cbw*512 + (lrow & 7)*2;     // byte base
  // read-side addressing: physical row of seq lrow is perm ^ (cb&7)
  const int perm  = ((lrow & 3) << 2) | (lrow >> 2);
  const int aoffE = ((perm ^ lk) * 16);         // even kf-block (key = lk)
                                                // odd kf-block: aoffE ^ 64

  // stage Whh0 frags into LDS (straight 16B copies)
  for (int i = tid; i < 8192; i += 512)
    ((uint4*)whh0_lds)[i] = ((const uint4*)whh0_f)[i];
  // zero all three h buffers (contiguous 24KB)
  for (int i = tid; i < 6144; i += 512) ((u32*)hA)[i] = 0;

  // W1 frags pinned into AGPRs (exactly 128): consumers are "a"-operand MFMAs.
  u32x4 w1a[4][8];
  #pragma unroll
  for (int g = 0; g < 4; ++g)
    #pragma unroll
    for (int kf = 0; kf < 8; ++kf)
      w1a[g][kf] = *(const u32x4*)(w1_f + ((((w*4+g)*8)+kf)*64 + l)*8);
  bf16x8 wih0r[4];
  #pragma unroll
  for (int g = 0; g < 4; ++g)
    wih0r[g] = *(const bf16x8*)(wih0_f + ((w*4+g)*64 + l)*8);
  float b0v[4], b1v[4];
  #pragma unroll
  for (int g = 0; g < 4; ++g) {
    b0v[g] = b0a[w*64 + g*16 + lrow];
    b1v[g] = b1a[w*64 + g*16 + lrow];
  }
  float c_a[2][4] = {{0,0,0,0},{0,0,0,0}};
  float c_b[2][4] = {{0,0,0,0},{0,0,0,0}};

  unsigned char* hbR = hB0;   // layer-1 h_prev (zero at t=0)
  unsigned char* hbW = hB1;

  __syncthreads();

  #pragma unroll 1
  for (int t = 0; t < T_STEPS; ++t) {
    // issue x loads first (L2-resident; consumed after the 32 hh-MFMAs below,
    // so latency hides under the matrix pipe; liveness is within-step only)
    const u16* xrow = xb + (size_t)(t*8192 + s0 + lrow)*8;
    bf16x8 xf0 = *(const bf16x8*)xrow;          // lanes lk>0: k>=8 rows of B are 0
    bf16x8 xf1 = *(const bf16x8*)(xrow + 128);  // +16 seqs

    // ---- layer 0: gates = b0 + hA@Whh0^T + x@Wih0^T ------------------------
    f32x4 acc[2][4];
    #pragma unroll
    for (int g = 0; g < 4; ++g) {
      acc[0][g] = (f32x4){b0v[g], b0v[g], b0v[g], b0v[g]};
      acc[1][g] = (f32x4){b0v[g], b0v[g], b0v[g], b0v[g]};
    }
    #pragma unroll
    for (int kf = 0; kf < 4; ++kf) {
      int ao = (kf*4 + lk)*512 + ((kf & 1) ? (aoffE ^ 64) : aoffE);
      bf16x8 a0 = *(const bf16x8*)(hA + ao);
      bf16x8 a1 = *(const bf16x8*)(hA + ao + 256);
      #pragma unroll
      for (int g = 0; g < 4; ++g) {
        bf16x8 bfr = *(const bf16x8*)(whh0_lds + ((w*16 + g*4 + kf)*64 + l)*8);
        acc[0][g] = mfma16(a0, bfr, acc[0][g]);
        acc[1][g] = mfma16(a1, bfr, acc[1][g]);
      }
    }
    #pragma unroll
    for (int g = 0; g < 4; ++g) {
      acc[0][g] = mfma16(xf0, wih0r[g], acc[0][g]);
      acc[1][g] = mfma16(xf1, wih0r[g], acc[1][g]);
    }
    __syncthreads();                       // (1) WAR: hA reads done
    ACT_BLOCK(acc, c_a, hA);               // act0 -> hA (new layer-0 h)
    __syncthreads();                       // (2) RAW: new hA visible

    // ---- layer 1: gates = b1 + hA@Wih1^T + hbR@Whh1^T (W1 in AGPRs) -------
    #pragma unroll
    for (int g = 0; g < 4; ++g) {
      acc[0][g] = (f32x4){b1v[g], b1v[g], b1v[g], b1v[g]};
      acc[1][g] = (f32x4){b1v[g], b1v[g], b1v[g], b1v[g]};
    }
    asm volatile("s_nop 1");               // VALU splat -> asm MFMA C-read gap
    #pragma unroll
    for (int kf = 0; kf < 8; ++kf) {
      const unsigned char* hs = (kf < 4) ? hA : hbR;
      int ao = ((kf & 3)*4 + lk)*512 + ((kf & 1) ? (aoffE ^ 64) : aoffE);
      bf16x8 a0 = *(const bf16x8*)(hs + ao);
      bf16x8 a1 = *(const bf16x8*)(hs + ao + 256);
      #pragma unroll
      for (int g = 0; g < 4; ++g) {
        mfma_agpr(acc[0][g], a0, w1a[g][kf]);
        mfma_agpr(acc[1][g], a1, w1a[g][kf]);
      }
    }
    asm volatile("s_nop 7\ns_nop 7");      // asm MFMA -> VALU read of acc
    // writes go to hbW (ping-pong): next step's bars order them vs t+1 readers
    ACT_BLOCK(acc, c_b, hbW);              // act1 -> hB[t&1]
    { unsigned char* tp = hbR; hbR = hbW; hbW = tp; }
  }
  __syncthreads();                         // final hB visible for the head

  // ---- head: out = sigmoid(h_final @ Weff^T + beff), sigma *= 0.5 ----------
  if (tid < BM*4) {
    int m = tid >> 2, o = tid & 3;
    const float* wr = weff + o*128;
    float d = beff[o];
    int rp = (m & 16) | ((m & 3) << 2) | ((m & 15) >> 2);   // physical row base
    #pragma unroll 4
    for (int kk = 0; kk < 16; ++kk) {
      bf16x8 hv = *(const bf16x8*)(hbR + kk*512 + (rp ^ (kk & 7))*16);
      #pragma unroll
      for (int j = 0; j < 8; ++j) d += bu2f((u16)hv[j]) * wr[kk*8 + j];
    }
    float v = fsig(d);
    if (o >= 2) v *= 0.5f;
    int s = s0 + m;
    out[(o >= 2 ? 16384 : 0) + s*2 + (o & 1)] = v;
  }
}

extern "C" void kernel_launch(void* const* d_in, const int* in_sizes, int n_in,
                              void* d_out, int out_size, void* d_ws, size_t ws_size,
                              hipStream_t stream) {
  (void)in_sizes; (void)n_in; (void)out_size; (void)ws_size;
  const float* in_tensor = (const float*)d_in[0];
  const float* Wih0 = (const float*)d_in[1];
  const float* Whh0 = (const float*)d_in[2];
  const float* bih0 = (const float*)d_in[3];
  const float* bhh0 = (const float*)d_in[4];
  const float* Wih1 = (const float*)d_in[5];
  const float* Whh1 = (const float*)d_in[6];
  const float* bih1 = (const float*)d_in[7];
  const float* bhh1 = (const float*)d_in[8];
  const float* muW1 = (const float*)d_in[9];
  const float* mub1 = (const float*)d_in[10];
  const float* muW2 = (const float*)d_in[11];
  const float* mub2 = (const float*)d_in[12];
  const float* sgW1 = (const float*)d_in[13];
  const float* sgb1 = (const float*)d_in[14];
  const float* sgW2 = (const float*)d_in[15];
  const float* sgb2 = (const float*)d_in[16];
  unsigned char* ws = (unsigned char*)d_ws;
  float* out = (float*)d_out;

  lstm_prep_w<<<dim3(111), dim3(256), 0, stream>>>(
      Wih0, Whh0, bih0, bhh0, Wih1, Whh1, bih1, bhh1,
      muW1, mub1, muW2, mub2, sgW1, sgb1, sgW2, sgb2, ws);
  lstm_prep_x<<<dim3(2048), dim3(256), 0, stream>>>(in_tensor, ws);

  (void)hipFuncSetAttribute((const void*)lstm_fused,
                            hipFuncAttributeMaxDynamicSharedMemorySize, LDS_BYTES);
  lstm_fused<<<dim3(256), dim3(512), LDS_BYTES, stream>>>(ws, out);
}

// Round 7
// 322.936 us; speedup vs baseline: 1.0465x; 1.0184x over previous
//
#include <hip/hip_runtime.h>
#include <hip/hip_bf16.h>

typedef unsigned short u16;
typedef unsigned int u32;
typedef __attribute__((ext_vector_type(8))) short bf16x8;
typedef __attribute__((ext_vector_type(4))) float f32x4;
typedef __attribute__((ext_vector_type(4))) unsigned u32x4;

#define T_STEPS 64
#define BN_TOT  8192
#define BM      32

// workspace byte offsets
#define OFF_WHH0  0u
#define OFF_WIH0  131072u
#define OFF_W1    163840u
#define OFF_B0    425984u
#define OFF_B1    428032u
#define OFF_WEFF  430080u
#define OFF_BEFF  432128u
#define OFF_XB    432192u

// LDS: whh0 frags (128KB) + 3 h buffers (8KB each, col-block-major)
#define HB        8192
#define LDS_BYTES (131072 + 3*HB)   // 155648

__device__ __forceinline__ u16 f2bu(float f) {
  unsigned u = __float_as_uint(f);
  unsigned r = (u + 0x7FFFu + ((u >> 16) & 1u)) >> 16;
  return (u16)r;
}
__device__ __forceinline__ float bu2f(u16 u) {
  return __uint_as_float(((unsigned)u) << 16);
}
__device__ __forceinline__ float fsig(float x) {
  return __builtin_amdgcn_rcpf(1.0f + __builtin_amdgcn_exp2f(-1.44269504f * x));
}
__device__ __forceinline__ float ftanh(float x) {
  return 1.0f - 2.0f * __builtin_amdgcn_rcpf(__builtin_amdgcn_exp2f(2.88539008f * x) + 1.0f);
}
__device__ __forceinline__ unsigned cvt_pk_bf16(float lo, float hi) {
  unsigned r;
  asm("v_cvt_pk_bf16_f32 %0, %1, %2" : "=v"(r) : "v"(lo), "v"(hi));
  return r;
}
__device__ __forceinline__ f32x4 mfma16(bf16x8 a, bf16x8 b, f32x4 c) {
  return __builtin_amdgcn_mfma_f32_16x16x32_bf16(a, b, c, 0, 0, 0);
}
// MFMA with B operand pinned in AGPRs -> W1 resident in accumulator file.
__device__ __forceinline__ void mfma_agpr(f32x4& c, const bf16x8& a, const u32x4& b) {
  asm("v_mfma_f32_16x16x32_bf16 %0, %1, %2, %0" : "+v"(c) : "v"(a), "a"(b));
}

union U16x8 { u16 u[8]; uint4 q; };

// ---------------- prep: weights -> fragment-ordered bf16, collapsed head ----
__global__ void lstm_prep_w(const float* Wih0, const float* Whh0,
                            const float* bih0, const float* bhh0,
                            const float* Wih1, const float* Whh1,
                            const float* bih1, const float* bhh1,
                            const float* muW1, const float* mub1,
                            const float* muW2, const float* mub2,
                            const float* sgW1, const float* sgb1,
                            const float* sgW2, const float* sgb2,
                            unsigned char* ws)
{
  int id = blockIdx.x * 256 + threadIdx.x;
  u16* whh0_f = (u16*)(ws + OFF_WHH0);
  u16* wih0_f = (u16*)(ws + OFF_WIH0);
  u16* w1_f   = (u16*)(ws + OFF_W1);
  float* b0   = (float*)(ws + OFF_B0);
  float* b1   = (float*)(ws + OFF_B1);
  float* weff = (float*)(ws + OFF_WEFF);
  float* beff = (float*)(ws + OFF_BEFF);

  if (id < 8192) {                       // Whh0 frags: [w][g][kf][lane][8]
    int fid = id >> 6, lane = id & 63;
    int w = fid >> 4, g = (fid >> 2) & 3, kf = fid & 3;
    int r = g*128 + w*16 + (lane & 15);
    int k = kf*32 + (lane >> 4)*8;
    const float* src = Whh0 + r*128 + k;
    U16x8 t;
    #pragma unroll
    for (int i = 0; i < 8; ++i) t.u[i] = f2bu(src[i]);
    ((uint4*)whh0_f)[id] = t.q;
  } else if (id < 10240) {               // Wih0 frags (K=8 in 32, zero-padded)
    int c = id - 8192; int fid = c >> 6, lane = c & 63;
    int w = fid >> 2, g = fid & 3;
    U16x8 t;
    #pragma unroll
    for (int i = 0; i < 8; ++i) t.u[i] = 0;
    if (lane < 16) {
      int r = g*128 + w*16 + lane;
      #pragma unroll
      for (int i = 0; i < 8; ++i) t.u[i] = f2bu(Wih0[r*8 + i]);
    }
    ((uint4*)wih0_f)[c] = t.q;
  } else if (id < 26624) {               // W1 = [Wih1 ; Whh1] frags, K=256
    int c = id - 10240; int fid = c >> 6, lane = c & 63;
    int w = fid >> 5, g = (fid >> 3) & 3, kf = fid & 7;
    int r = g*128 + w*16 + (lane & 15);
    int k = kf*32 + (lane >> 4)*8;
    const float* src = (k < 128) ? (Wih1 + r*128 + k) : (Whh1 + r*128 + (k-128));
    U16x8 t;
    #pragma unroll
    for (int i = 0; i < 8; ++i) t.u[i] = f2bu(src[i]);
    ((uint4*)w1_f)[c] = t.q;
  } else if (id < 27136) {               // b0 arranged
    int i = id - 26624; int w = i >> 6, g = (i >> 4) & 3, cc = i & 15;
    int r = g*128 + w*16 + cc;
    b0[i] = bih0[r] + bhh0[r];
  } else if (id < 27648) {               // b1 arranged
    int i = id - 27136; int w = i >> 6, g = (i >> 4) & 3, cc = i & 15;
    int r = g*128 + w*16 + cc;
    b1[i] = bih1[r] + bhh1[r];
  } else if (id < 28160) {               // collapsed head W: [4][128]
    int i = id - 27648; int o = i >> 7, k = i & 127;
    const float* W1p = (o < 2) ? muW1 : sgW1;
    const float* W2p = (o < 2) ? muW2 : sgW2;
    int oo = o & 1;
    float s = 0.f;
    for (int m = 0; m < 64; ++m) s += W2p[oo*64 + m] * W1p[m*128 + k];
    weff[i] = s;
  } else if (id < 28164) {               // collapsed head bias [4]
    int o = id - 28160; int oo = o & 1;
    const float* W2p = (o < 2) ? muW2 : sgW2;
    const float* b1p = (o < 2) ? mub1 : sgb1;
    const float* b2p = (o < 2) ? mub2 : sgb2;
    float s = b2p[oo];
    for (int m = 0; m < 64; ++m) s += W2p[oo*64 + m] * b1p[m];
    beff[o] = s;
  }
}

// ---------------- prep: in_tensor [B,T,N,D] fp32 -> xb [T, BN, 8] bf16 ------
__global__ void lstm_prep_x(const float* in, unsigned char* ws)
{
  int id = blockIdx.x * 256 + threadIdx.x;     // < 524288
  if (id >= T_STEPS * BN_TOT) return;
  int t = id >> 13, s = id & 8191, b = s >> 9, n = s & 511;
  const float* src = in + (((b*64) + t)*512 + n)*8;
  U16x8 v;
  #pragma unroll
  for (int i = 0; i < 8; ++i) v.u[i] = f2bu(src[i]);
  *(uint4*)(ws + OFF_XB + (size_t)id * 16) = v.q;
}

// ---------------- main: fused 2-layer LSTM + head, persistent over T --------
// h layout (R5, empirically best conflict count): col-block-major.
//   addr(row=seq, col) = (col>>3)*512 + row*16 + (col&7)*2
// A-frag b128 read: 16 lanes x contiguous rows -> ~free.
// ACT u16 store: measured ~4e6 total conflict cycles (negligible).
#define ACT_BLOCK(ACC, CS, HBASE)                                   \
  { _Pragma("unroll")                                               \
    for (int mf = 0; mf < 2; ++mf) {                                \
      float hq[4];                                                  \
      _Pragma("unroll")                                             \
      for (int q = 0; q < 4; ++q) {                                 \
        float gi = fsig(ACC[mf][0][q]);                             \
        float gf = fsig(ACC[mf][1][q]);                             \
        float gg = ftanh(ACC[mf][2][q]);                            \
        float go = fsig(ACC[mf][3][q]);                             \
        float c  = gf * CS[mf][q] + gi * gg;                        \
        CS[mf][q] = c;                                              \
        hq[q] = go * ftanh(c);                                      \
      }                                                             \
      unsigned p01 = cvt_pk_bf16(hq[0], hq[1]);                     \
      unsigned p23 = cvt_pk_bf16(hq[2], hq[3]);                     \
      int rb = (mf*16 + lk*4);                                      \
      *(u16*)(HBASE + wb + (rb  )*16) = (u16)p01;                   \
      *(u16*)(HBASE + wb + (rb+1)*16) = (u16)(p01 >> 16);           \
      *(u16*)(HBASE + wb + (rb+2)*16) = (u16)p23;                   \
      *(u16*)(HBASE + wb + (rb+3)*16) = (u16)(p23 >> 16);           \
    } }

__global__ __launch_bounds__(512, 2) void lstm_fused(const unsigned char* ws, float* out)
{
  extern __shared__ unsigned char lds[];
  u16* whh0_lds = (u16*)lds;                 // [w][g][kf][lane][8] frags, 128KB
  unsigned char* hA  = lds + 131072;
  unsigned char* hB0 = hA + HB;
  unsigned char* hB1 = hB0 + HB;

  const u16* whh0_f = (const u16*)(ws + OFF_WHH0);
  const u16* wih0_f = (const u16*)(ws + OFF_WIH0);
  const u16* w1_f   = (const u16*)(ws + OFF_W1);
  const float* b0a  = (const float*)(ws + OFF_B0);
  const float* b1a  = (const float*)(ws + OFF_B1);
  const float* weff = (const float*)(ws + OFF_WEFF);
  const float* beff = (const float*)(ws + OFF_BEFF);
  const u16* xb     = (const u16*)(ws + OFF_XB);

  const int tid = threadIdx.x;
  const int w = tid >> 6, l = tid & 63;
  const int lrow = l & 15, lk = l >> 4;
  const int s0 = blockIdx.x * BM;
  // per-thread byte bases into col-block-major h buffers
  const int wb = (w*2 + (lrow >> 3))*512 + (lrow & 7)*2;   // ACT write base
  const int ra = lk*512 + lrow*16;                          // A-read base

  // ---- prologue, pressure-controlled -------------------------------------
  // 1) stage Whh0 frags into LDS (streaming copies, limited unroll)
  #pragma unroll 2
  for (int i = tid; i < 8192; i += 512)
    ((uint4*)whh0_lds)[i] = ((const uint4*)whh0_f)[i];
  // 2) zero all three h buffers
  for (int i = tid; i < 6144; i += 512) ((u32*)hA)[i] = 0;
  __builtin_amdgcn_sched_barrier(0);

  // 3) W1 frags into AGPRs in 8 batches of 4 (16 VGPR temps live max).
  //    sched_barrier(0) stops the scheduler hoisting all 32 loads first,
  //    which in R5/R6 spilled ~27 dwords/thread (14 MB WRITE_SIZE).
  u32x4 w1a[4][8];
  #pragma unroll
  for (int kf = 0; kf < 8; ++kf) {
    #pragma unroll
    for (int g = 0; g < 4; ++g)
      w1a[g][kf] = *(const u32x4*)(w1_f + ((((w*4+g)*8)+kf)*64 + l)*8);
    __builtin_amdgcn_sched_barrier(0);
  }

  // 4) small register weights
  bf16x8 wih0r[4];
  #pragma unroll
  for (int g = 0; g < 4; ++g)
    wih0r[g] = *(const bf16x8*)(wih0_f + ((w*4+g)*64 + l)*8);
  float b0v[4], b1v[4];
  #pragma unroll
  for (int g = 0; g < 4; ++g) {
    b0v[g] = b0a[w*64 + g*16 + lrow];
    b1v[g] = b1a[w*64 + g*16 + lrow];
  }
  float c_a[2][4] = {{0,0,0,0},{0,0,0,0}};
  float c_b[2][4] = {{0,0,0,0},{0,0,0,0}};

  unsigned char* hbR = hB0;   // layer-1 h_prev (zero at t=0)
  unsigned char* hbW = hB1;

  __syncthreads();

  #pragma unroll 1
  for (int t = 0; t < T_STEPS; ++t) {
    // issue x loads first (L2-resident; consumed after the 32 hh-MFMAs below,
    // so latency hides under the matrix pipe; liveness is within-step only)
    const u16* xrow = xb + (size_t)(t*8192 + s0 + lrow)*8;
    bf16x8 xf0 = *(const bf16x8*)xrow;          // lanes lk>0: k>=8 rows of B are 0
    bf16x8 xf1 = *(const bf16x8*)(xrow + 128);  // +16 seqs

    // ---- layer 0: gates = b0 + hA@Whh0^T + x@Wih0^T ------------------------
    f32x4 acc[2][4];
    #pragma unroll
    for (int g = 0; g < 4; ++g) {
      acc[0][g] = (f32x4){b0v[g], b0v[g], b0v[g], b0v[g]};
      acc[1][g] = (f32x4){b0v[g], b0v[g], b0v[g], b0v[g]};
    }
    #pragma unroll
    for (int kf = 0; kf < 4; ++kf) {
      bf16x8 a0 = *(const bf16x8*)(hA + (kf*4)*512 + ra);
      bf16x8 a1 = *(const bf16x8*)(hA + (kf*4)*512 + ra + 256);
      #pragma unroll
      for (int g = 0; g < 4; ++g) {
        bf16x8 bfr = *(const bf16x8*)(whh0_lds + ((w*16 + g*4 + kf)*64 + l)*8);
        acc[0][g] = mfma16(a0, bfr, acc[0][g]);
        acc[1][g] = mfma16(a1, bfr, acc[1][g]);
      }
    }
    #pragma unroll
    for (int g = 0; g < 4; ++g) {
      acc[0][g] = mfma16(xf0, wih0r[g], acc[0][g]);
      acc[1][g] = mfma16(xf1, wih0r[g], acc[1][g]);
    }
    __syncthreads();                       // (1) WAR: hA reads done
    ACT_BLOCK(acc, c_a, hA);               // act0 -> hA (new layer-0 h)
    __syncthreads();                       // (2) RAW: new hA visible

    // ---- layer 1: gates = b1 + hA@Wih1^T + hbR@Whh1^T (W1 in AGPRs) -------
    #pragma unroll
    for (int g = 0; g < 4; ++g) {
      acc[0][g] = (f32x4){b1v[g], b1v[g], b1v[g], b1v[g]};
      acc[1][g] = (f32x4){b1v[g], b1v[g], b1v[g], b1v[g]};
    }
    asm volatile("s_nop 1");               // VALU splat -> asm MFMA C-read gap
    #pragma unroll
    for (int kf = 0; kf < 8; ++kf) {
      const unsigned char* hs = (kf < 4) ? hA : hbR;
      int cb = (kf & 3)*4;
      bf16x8 a0 = *(const bf16x8*)(hs + cb*512 + ra);
      bf16x8 a1 = *(const bf16x8*)(hs + cb*512 + ra + 256);
      #pragma unroll
      for (int g = 0; g < 4; ++g) {
        mfma_agpr(acc[0][g], a0, w1a[g][kf]);
        mfma_agpr(acc[1][g], a1, w1a[g][kf]);
      }
    }
    asm volatile("s_nop 7\ns_nop 7");      // asm MFMA -> VALU read of acc
    // writes go to hbW (ping-pong): next step's bars order them vs t+1 readers
    ACT_BLOCK(acc, c_b, hbW);              // act1 -> hB[t&1]
    { unsigned char* tp = hbR; hbR = hbW; hbW = tp; }
  }
  __syncthreads();                         // final hB visible for the head

  // ---- head: out = sigmoid(h_final @ Weff^T + beff), sigma *= 0.5 ----------
  if (tid < BM*4) {
    int m = tid >> 2, o = tid & 3;
    const float* wr = weff + o*128;
    float d = beff[o];
    #pragma unroll 4
    for (int kk = 0; kk < 16; ++kk) {
      bf16x8 hv = *(const bf16x8*)(hbR + kk*512 + m*16);
      #pragma unroll
      for (int j = 0; j < 8; ++j) d += bu2f((u16)hv[j]) * wr[kk*8 + j];
    }
    float v = fsig(d);
    if (o >= 2) v *= 0.5f;
    int s = s0 + m;
    out[(o >= 2 ? 16384 : 0) + s*2 + (o & 1)] = v;
  }
}

extern "C" void kernel_launch(void* const* d_in, const int* in_sizes, int n_in,
                              void* d_out, int out_size, void* d_ws, size_t ws_size,
                              hipStream_t stream) {
  (void)in_sizes; (void)n_in; (void)out_size; (void)ws_size;
  const float* in_tensor = (const float*)d_in[0];
  const float* Wih0 = (const float*)d_in[1];
  const float* Whh0 = (const float*)d_in[2];
  const float* bih0 = (const float*)d_in[3];
  const float* bhh0 = (const float*)d_in[4];
  const float* Wih1 = (const float*)d_in[5];
  const float* Whh1 = (const float*)d_in[6];
  const float* bih1 = (const float*)d_in[7];
  const float* bhh1 = (const float*)d_in[8];
  const float* muW1 = (const float*)d_in[9];
  const float* mub1 = (const float*)d_in[10];
  const float* muW2 = (const float*)d_in[11];
  const float* mub2 = (const float*)d_in[12];
  const float* sgW1 = (const float*)d_in[13];
  const float* sgb1 = (const float*)d_in[14];
  const float* sgW2 = (const float*)d_in[15];
  const float* sgb2 = (const float*)d_in[16];
  unsigned char* ws = (unsigned char*)d_ws;
  float* out = (float*)d_out;

  lstm_prep_w<<<dim3(111), dim3(256), 0, stream>>>(
      Wih0, Whh0, bih0, bhh0, Wih1, Whh1, bih1, bhh1,
      muW1, mub1, muW2, mub2, sgW1, sgb1, sgW2, sgb2, ws);
  lstm_prep_x<<<dim3(2048), dim3(256), 0, stream>>>(in_tensor, ws);

  (void)hipFuncSetAttribute((const void*)lstm_fused,
                            hipFuncAttributeMaxDynamicSharedMemorySize, LDS_BYTES);
  lstm_fused<<<dim3(256), dim3(512), LDS_BYTES, stream>>>(ws, out);
}